// Round 9
// baseline (288.276 us; speedup 1.0000x reference)
//
#include <hip/hip_runtime.h>
#include <hip/hip_bf16.h>

// GraphSAGE 2-layer forward. N=100000, E=1250000, 64 -> 64 -> 32, fp32.
//
// Round-9: (a) dense2 fused into agg64 epilogue (h1 never touches memory;
// per-lane register W-column dot products), (b) p2 at BW=256 for occupancy,
// (c) s2 lives in d_out (agg32 updates in place) so nothing aliases t1n.
//   zero    : gcursor = 0
//   p1      : bucket edges by dst>>8, pack (src<<8)|rel
//   p2      : per-bucket base (inline prefix) + LDS count/scan -> row_start + csr
//   dense1  : bufA = x@Ws1+b1 (f32), t1n = bf16(x@Wn1)  (MFMA split-bf16)
//   agg64f  : h1 = relu(bufA + mean t1n[src]) in-wave; s2(d_out) = h1@Ws2+b2,
//             t2n = bf16(h1@Wn2)   (W columns in VGPRs, h1 via per-wave LDS)
//   agg32   : out = s2 + mean t2n[src]   (in-place on d_out)

#define NF 64
#define BW 256            // bucket width (nodes); rel = dst & 255
#define BSH 8
#define MAXB 512          // max buckets (LDS arrays)
#define CAPMAX 8192       // max edges per bucket region (mean 3197)
#define P1_CHUNK 4096

typedef __attribute__((ext_vector_type(8))) short short8;
typedef __attribute__((ext_vector_type(8))) unsigned short ushort8v;
typedef __attribute__((ext_vector_type(4))) float floatx4;

__device__ __forceinline__ short bf16hi(float v) {
    __hip_bfloat16 h = __float2bfloat16(v);
    return *(short*)&h;
}
__device__ __forceinline__ float bf2f(short s) {
    __hip_bfloat16 h = *(__hip_bfloat16*)&s;
    return __bfloat162float(h);
}
__device__ __forceinline__ float bits2f(unsigned short u) {
    unsigned int x = ((unsigned int)u) << 16;
    union { unsigned int i; float f; } c; c.i = x; return c.f;
}

// ---------------- zero ----------------

__global__ __launch_bounds__(512) void zero_kernel(int* __restrict__ g) {
    if (threadIdx.x < MAXB) g[threadIdx.x] = 0;
}

// ---------------- CSR build: counting sort ----------------

__global__ __launch_bounds__(256) void p1_bucket_kernel(const int* __restrict__ src,
                                                        const int* __restrict__ dst,
                                                        int* __restrict__ gcursor,
                                                        unsigned* __restrict__ bucket,
                                                        int E, int nbuckets) {
    __shared__ int cnt[MAXB];
    __shared__ int cbase[MAXB];
    const int beg = blockIdx.x * P1_CHUNK;
    const int end = min(E, beg + P1_CHUNK);
    for (int i = threadIdx.x; i < nbuckets; i += 256) cnt[i] = 0;
    __syncthreads();
    for (int e = beg + threadIdx.x; e < end; e += 256)
        atomicAdd(&cnt[dst[e] >> BSH], 1);
    __syncthreads();
    for (int i = threadIdx.x; i < nbuckets; i += 256) {
        int c = cnt[i];
        cbase[i] = c ? atomicAdd(&gcursor[i], c) : 0;
        cnt[i] = 0;                              // reuse as local cursor
    }
    __syncthreads();
    for (int e = beg + threadIdx.x; e < end; e += 256) {
        int d = dst[e];
        int r = d >> BSH;
        int p = cbase[r] + atomicAdd(&cnt[r], 1);
        if (p < CAPMAX)                          // clamp: no OOB even if skewed
            bucket[(size_t)r * CAPMAX + p] = ((unsigned)src[e] << BSH) | (unsigned)(d & (BW - 1));
    }
}

// p2: one block per 256-node bucket; exclusive row_start segment + csr window.
__global__ __launch_bounds__(256) void p2_csr_kernel(const unsigned* __restrict__ bucket,
                                                     const int* __restrict__ gcursor,
                                                     int* __restrict__ row_start,
                                                     int* __restrict__ csr_src,
                                                     int N, int nbuckets) {
    __shared__ unsigned stage[CAPMAX];   // 32 KB
    __shared__ int cnt[BW];
    __shared__ int excl[BW];
    const int r = blockIdx.x;
    const int tid = threadIdx.x;

    // base = sum_{i<r} min(gcursor[i], CAPMAX)   (excl[] as scratch)
    int partial = 0;
    for (int i = tid; i < r; i += 256) partial += min(gcursor[i], CAPMAX);
    excl[tid] = partial;
    __syncthreads();
    for (int off = 128; off > 0; off >>= 1) {
        if (tid < off) excl[tid] += excl[tid + off];
        __syncthreads();
    }
    const int base = excl[0];
    const int sz = min(gcursor[r], CAPMAX);
    const unsigned* bsrc = bucket + (size_t)r * CAPMAX;
    __syncthreads();

    cnt[tid] = 0;
    __syncthreads();
    for (int i = tid; i < sz; i += 256) {
        unsigned v = bsrc[i];
        stage[i] = v;
        atomicAdd(&cnt[v & (BW - 1)], 1);
    }
    __syncthreads();
    // inclusive scan (Hillis-Steele, 1 elem/thread since BW == blockDim)
    excl[tid] = cnt[tid];
    __syncthreads();
    for (int off = 1; off < BW; off <<= 1) {
        int v0 = (tid >= off) ? excl[tid - off] : 0;
        __syncthreads();
        excl[tid] += v0;
        __syncthreads();
    }
    int node = r * BW + tid;
    if (node < N) row_start[node] = base + excl[tid] - cnt[tid];
    if (r == nbuckets - 1 && tid == 0) row_start[N] = base + sz;
    __syncthreads();
    cnt[tid] = excl[tid] - cnt[tid];             // exclusive cursors
    __syncthreads();
    for (int i = tid; i < sz; i += 256) {
        unsigned v = stage[i];
        int p = atomicAdd(&cnt[v & (BW - 1)], 1);
        csr_src[base + p] = (int)(v >> BSH);     // window owned by this block only
    }
}

// ---------------- MFMA dense1: [N][64] @ [64][128] ----------
// A layout: A[m=lane&15][k=(lane>>4)*8+j]; C/D: col=lane&15, row=(lane>>4)*4+reg.
// Weights split+transposed to bf16 hi/lo in LDS ([n][72] pad, 2-way banks free).
// Tiles t<4 -> f32 xs + bias; t>=4 -> bf16 t1n (neighbor transform).

__global__ __launch_bounds__(256) void dense1_mfma_kernel(
        const float* __restrict__ X,                 // [N][64]
        const float* __restrict__ Wself,             // [64][64] k-major
        const float* __restrict__ Wneigh,            // [64][64] k-major
        const float* __restrict__ bias,              // [64]
        float* __restrict__ outA,                    // [N][64] f32
        unsigned short* __restrict__ outB,           // [N][64] bf16 bits
        int N) {
    constexpr int NT = 8, NSELF = 4, NO = 128, HALF = 64;
    __shared__ unsigned short wh[NO * 72];
    __shared__ unsigned short wl[NO * 72];
    const int tid = threadIdx.x;
    for (int i = tid; i < NO * 64; i += 256) {
        int n = i & (NO - 1), k = i / NO;
        float v = (n < HALF) ? Wself[k * HALF + n] : Wneigh[k * HALF + (n - HALF)];
        short hv = bf16hi(v);
        wh[n * 72 + k] = (unsigned short)hv;
        wl[n * 72 + k] = (unsigned short)bf16hi(v - bf2f(hv));
    }

    const int lane = tid & 63;
    const int wid  = tid >> 6;
    const int m = lane & 15, quad = lane >> 4;
    const int rowblk = blockIdx.x * 128 + wid * 32;

    floatx4 acc[2][NT];
    #pragma unroll
    for (int rt = 0; rt < 2; ++rt)
        #pragma unroll
        for (int t = 0; t < NT; ++t) acc[rt][t] = (floatx4)(0.f);

    short8 ah[2][2], al[2][2];
    #pragma unroll
    for (int rt = 0; rt < 2; ++rt) {
        int r = rowblk + rt * 16 + m;
        if (r >= N) r = N - 1;                       // clamped load, store guarded
        const float* xp = X + (size_t)r * 64 + quad * 8;
        #pragma unroll
        for (int h = 0; h < 2; ++h) {
            floatx4 f0 = *(const floatx4*)(xp + h * 32);
            floatx4 f1 = *(const floatx4*)(xp + h * 32 + 4);
            short8 hi, lo;
            #pragma unroll
            for (int j = 0; j < 4; ++j) {
                short hv = bf16hi(f0[j]);
                hi[j] = hv; lo[j] = bf16hi(f0[j] - bf2f(hv));
                short hv2 = bf16hi(f1[j]);
                hi[4 + j] = hv2; lo[4 + j] = bf16hi(f1[j] - bf2f(hv2));
            }
            ah[rt][h] = hi; al[rt][h] = lo;
        }
    }
    __syncthreads();                                 // weights staged

    #pragma unroll
    for (int t = 0; t < NT; ++t) {
        int n = t * 16 + m;
        const unsigned short* ph = wh + n * 72 + quad * 8;
        const unsigned short* pl = wl + n * 72 + quad * 8;
        #pragma unroll
        for (int h = 0; h < 2; ++h) {
            short8 bh = *(const short8*)(ph + h * 32);
            short8 bl = *(const short8*)(pl + h * 32);
            #pragma unroll
            for (int rt = 0; rt < 2; ++rt) {
                acc[rt][t] = __builtin_amdgcn_mfma_f32_16x16x32_bf16(ah[rt][h], bh, acc[rt][t], 0, 0, 0);
                acc[rt][t] = __builtin_amdgcn_mfma_f32_16x16x32_bf16(al[rt][h], bh, acc[rt][t], 0, 0, 0);
                acc[rt][t] = __builtin_amdgcn_mfma_f32_16x16x32_bf16(ah[rt][h], bl, acc[rt][t], 0, 0, 0);
            }
        }
    }

    #pragma unroll
    for (int rt = 0; rt < 2; ++rt) {
        #pragma unroll
        for (int t = 0; t < NT; ++t) {
            #pragma unroll
            for (int r4 = 0; r4 < 4; ++r4) {
                int row = rowblk + rt * 16 + quad * 4 + r4;
                if (row < N) {
                    if (t < NSELF) {
                        int col = t * 16 + m;
                        outA[(size_t)row * 64 + col] = acc[rt][t][r4] + bias[col];
                    } else {
                        int col = (t - NSELF) * 16 + m;
                        outB[(size_t)row * 64 + col] = (unsigned short)bf16hi(acc[rt][t][r4]);
                    }
                }
            }
        }
    }
}

// ---------------- fused agg64 + dense2 ----------------
// Wave per node: gather mean of t1n rows (bf16), h1 = relu(xs + mean) held in
// a per-wave LDS row; each lane then computes one layer-2 output column as a
// 64-FMA dot with its register-resident W column. lane<32 -> s2(+b2) f32 to
// d_out; lane>=32 -> t2n bf16.

__global__ __launch_bounds__(256) void agg64_fused_kernel(
        const unsigned short* __restrict__ t1n,      // [N][64] bf16 bits
        const float* __restrict__ xs,                // [N][64] self+bias
        const int* __restrict__ row_start,
        const int* __restrict__ csr_src,
        const float* __restrict__ Ws2,               // [64][32] k-major
        const float* __restrict__ Wn2,               // [64][32] k-major
        const float* __restrict__ b2,                // [32]
        float* __restrict__ s2,                      // [N][32] (d_out)
        unsigned short* __restrict__ t2n,            // [N][32] bf16 bits
        int N) {
    __shared__ float w2[64 * 64];                    // 16 KB: w2[k][l<32:Ws2 | l>=32:Wn2]
    __shared__ float h1s[4][64];                     // per-wave h1 row
    const int tid = threadIdx.x;
    for (int i = tid; i < 64 * 64; i += 256) {
        int k = i >> 6, l = i & 63;
        w2[i] = (l < 32) ? Ws2[k * 32 + l] : Wn2[k * 32 + (l - 32)];
    }
    __syncthreads();

    const int lane = tid & 63;
    const int wid  = tid >> 6;
    // W column -> registers (one-time; w2[k*64+lane] banks = lane%32, 2-way free)
    float wcol[64];
    #pragma unroll
    for (int k = 0; k < 64; ++k) wcol[k] = w2[k * 64 + lane];

    int n = (blockIdx.x * blockDim.x + tid) >> 6;
    if (n >= N) return;
    int g = lane >> 3, c = lane & 7;                 // lane covers feats c*8..c*8+7
    int beg = row_start[n], end = row_start[n + 1];
    float acc[8] = {0.f, 0.f, 0.f, 0.f, 0.f, 0.f, 0.f, 0.f};
    for (int j = beg + g; j < end; j += 16) {
        int j2 = j + 8;
        int s0 = csr_src[j];
        ushort8v u0 = *(const ushort8v*)(t1n + (size_t)s0 * 64 + c * 8);
        if (j2 < end) {
            int s1 = csr_src[j2];
            ushort8v u1 = *(const ushort8v*)(t1n + (size_t)s1 * 64 + c * 8);
            #pragma unroll
            for (int i = 0; i < 8; ++i) acc[i] += bits2f(u0[i]) + bits2f(u1[i]);
        } else {
            #pragma unroll
            for (int i = 0; i < 8; ++i) acc[i] += bits2f(u0[i]);
        }
    }
    #pragma unroll
    for (int i = 0; i < 8; ++i) {                    // butterfly: ALL lanes get sums
        float v = acc[i];
        v += __shfl_xor(v, 8);
        v += __shfl_xor(v, 16);
        v += __shfl_xor(v, 32);
        acc[i] = v;
    }
    float invd = 1.0f / fmaxf((float)(end - beg), 1.0f);
    size_t o = (size_t)n * 64 + c * 8;
    floatx4 x0 = *(const floatx4*)(xs + o);          // 8 groups same addr: coalesced once
    floatx4 x1 = *(const floatx4*)(xs + o + 4);
    floatx4 h0, h1v;
    #pragma unroll
    for (int i = 0; i < 4; ++i) {
        h0[i]  = fmaxf(x0[i] + acc[i] * invd, 0.f);
        h1v[i] = fmaxf(x1[i] + acc[4 + i] * invd, 0.f);
    }
    if (g == 0) {                                    // lanes 0..7 write full h1 row
        *(floatx4*)&h1s[wid][c * 8]     = h0;
        *(floatx4*)&h1s[wid][c * 8 + 4] = h1v;
    }
    // same-wave LDS write->read; compiler orders via lgkmcnt
    float o2 = (lane < 32) ? b2[lane] : 0.f;
    #pragma unroll
    for (int q = 0; q < 16; ++q) {
        floatx4 hq = *(const floatx4*)&h1s[wid][q * 4];   // broadcast read
        #pragma unroll
        for (int jj = 0; jj < 4; ++jj) o2 += hq[jj] * wcol[q * 4 + jj];
    }
    if (lane < 32) s2[(size_t)n * 32 + lane] = o2;
    else           t2n[(size_t)n * 32 + (lane - 32)] = (unsigned short)bf16hi(o2);
}

// ---------------- agg32: out = s2 + mean t2n[src], in place on d_out --------

__global__ __launch_bounds__(256) void agg32_kernel(float* io,  // s2 -> out, [N][32]
                                                    const unsigned short* __restrict__ t2n,
                                                    const int* __restrict__ row_start,
                                                    const int* __restrict__ csr_src, int N) {
    int n = (blockIdx.x * blockDim.x + threadIdx.x) >> 6;
    if (n >= N) return;
    int lane = threadIdx.x & 63;
    int g = lane >> 2, c = lane & 3;                 // lane covers feats c*8..c*8+7
    int beg = row_start[n], end = row_start[n + 1];
    float acc[8] = {0.f, 0.f, 0.f, 0.f, 0.f, 0.f, 0.f, 0.f};
    for (int j = beg + g; j < end; j += 32) {
        int j2 = j + 16;
        int s0 = csr_src[j];
        ushort8v u0 = *(const ushort8v*)(t2n + (size_t)s0 * 32 + c * 8);
        if (j2 < end) {
            int s1 = csr_src[j2];
            ushort8v u1 = *(const ushort8v*)(t2n + (size_t)s1 * 32 + c * 8);
            #pragma unroll
            for (int i = 0; i < 8; ++i) acc[i] += bits2f(u0[i]) + bits2f(u1[i]);
        } else {
            #pragma unroll
            for (int i = 0; i < 8; ++i) acc[i] += bits2f(u0[i]);
        }
    }
    #pragma unroll
    for (int i = 0; i < 8; ++i) {
        float v = acc[i];
        v += __shfl_xor(v, 4);
        v += __shfl_xor(v, 8);
        v += __shfl_xor(v, 16);
        v += __shfl_xor(v, 32);
        acc[i] = v;
    }
    if (g == 0) {
        float inv = 1.0f / fmaxf((float)(end - beg), 1.0f);
        size_t o = (size_t)n * 32 + c * 8;
        floatx4 s0 = *(const floatx4*)(io + o);
        floatx4 s1 = *(const floatx4*)(io + o + 4);
        floatx4 r0, r1;
        #pragma unroll
        for (int i = 0; i < 4; ++i) {
            r0[i] = s0[i] + acc[i] * inv;
            r1[i] = s1[i] + acc[4 + i] * inv;
        }
        *(floatx4*)(io + o) = r0;
        *(floatx4*)(io + o + 4) = r1;
    }
}

// ---------------- fallback (round-2 atomic path) ----------------

__global__ __launch_bounds__(256) void deg_kernel(const int* __restrict__ dst,
                                                  float* __restrict__ deg, int E) {
    int e = blockIdx.x * blockDim.x + threadIdx.x;
    if (e < E) atomicAdd(&deg[dst[e]], 1.0f);
}

__global__ __launch_bounds__(256) void agg_atomic_kernel(const float* __restrict__ feats,
                                                         const int* __restrict__ src,
                                                         const int* __restrict__ dst,
                                                         float* __restrict__ agg, int E) {
    int tid = blockIdx.x * blockDim.x + threadIdx.x;
    if (tid >= E * NF) return;
    int e = tid >> 6, f = tid & 63;
    atomicAdd(&agg[(size_t)dst[e] * NF + f], feats[(size_t)src[e] * NF + f]);
}

__global__ __launch_bounds__(256) void layer1_fb_kernel(const float* __restrict__ x,
                                                        const float* __restrict__ agg,
                                                        const float* __restrict__ deg,
                                                        const float* __restrict__ Wself,
                                                        const float* __restrict__ Wneigh,
                                                        const float* __restrict__ b,
                                                        float* __restrict__ h1, int N) {
    int tid = blockIdx.x * blockDim.x + threadIdx.x;
    if (tid >= N * NF) return;
    int n = tid >> 6, c = tid & 63;
    float inv = 1.0f / fmaxf(deg[n], 1.0f);
    const float* xrow = x + (size_t)n * NF;
    const float* arow = agg + (size_t)n * NF;
    float acc = b[c];
    #pragma unroll
    for (int k = 0; k < NF; ++k) {
        acc += xrow[k] * Wself[k * NF + c];
        acc += (arow[k] * inv) * Wneigh[k * NF + c];
    }
    h1[tid] = fmaxf(acc, 0.f);
}

__global__ __launch_bounds__(256) void layer2_fb_kernel(const float* __restrict__ h1,
                                                        const float* __restrict__ agg,
                                                        const float* __restrict__ deg,
                                                        const float* __restrict__ Wself,
                                                        const float* __restrict__ Wneigh,
                                                        const float* __restrict__ b,
                                                        float* __restrict__ out, int N) {
    int tid = blockIdx.x * blockDim.x + threadIdx.x;
    if (tid >= N * 32) return;
    int n = tid >> 5, c = tid & 31;
    float inv = 1.0f / fmaxf(deg[n], 1.0f);
    const float* hrow = h1 + (size_t)n * NF;
    const float* arow = agg + (size_t)n * NF;
    float acc = b[c];
    #pragma unroll
    for (int k = 0; k < NF; ++k) {
        acc += hrow[k] * Wself[k * 32 + c];
        acc += (arow[k] * inv) * Wneigh[k * 32 + c];
    }
    out[tid] = acc;
}

// ---------------- launch ----------------

extern "C" void kernel_launch(void* const* d_in, const int* in_sizes, int n_in,
                              void* d_out, int out_size, void* d_ws, size_t ws_size,
                              hipStream_t stream) {
    const float* x        = (const float*)d_in[0];
    const int*   src      = (const int*)d_in[1];
    const int*   dst      = (const int*)d_in[2];
    const float* W_self1  = (const float*)d_in[3];
    const float* W_neigh1 = (const float*)d_in[4];
    const float* b1       = (const float*)d_in[5];
    const float* W_self2  = (const float*)d_in[6];
    const float* W_neigh2 = (const float*)d_in[7];
    const float* b2       = (const float*)d_in[8];
    float* out = (float*)d_out;

    const int N = in_sizes[0] / NF;          // 100000
    const int E = in_sizes[1];               // 1250000
    const int nbuckets = (N + BW - 1) / BW;  // 391

    // ws layout; every segment 16B-aligned
    const size_t rsPad = ((size_t)N + 8) & ~7ull;
    int* gcursor   = (int*)d_ws;                      // [MAXB]
    int* row_start = gcursor + MAXB;                  // [N+1] padded
    int* csr_src   = row_start + rsPad;               // [E]
    float* bufA = (float*)(csr_src + (((size_t)E + 7) & ~7ull));  // xs (f32)
    unsigned* bucket = (unsigned*)bufA;               // [nbuckets][CAPMAX], dead before dense1
    unsigned short* t1n = (unsigned short*)(bufA + (size_t)N * NF);  // [N][64] bf16
    unsigned short* t2n = t1n + (size_t)N * NF;                      // [N][32] bf16
    size_t need = (size_t)((char*)(t2n + (size_t)N * 32) - (char*)d_ws);  // ~50.4 MB

    bool fast = ws_size >= need
             && nbuckets <= MAXB
             && (size_t)nbuckets * CAPMAX <= (size_t)N * NF      // bucket fits in bufA alias
             && (size_t)E * 2 / (size_t)nbuckets <= CAPMAX       // 2x headroom over mean
             && N < (1 << 24)                                    // src fits in 24 bits
             && out_size >= N * 32;

    if (fast) {
        zero_kernel<<<1, 512, 0, stream>>>(gcursor);
        p1_bucket_kernel<<<(E + P1_CHUNK - 1) / P1_CHUNK, 256, 0, stream>>>(
            src, dst, gcursor, bucket, E, nbuckets);
        p2_csr_kernel<<<nbuckets, 256, 0, stream>>>(bucket, gcursor,
                                                    row_start, csr_src, N, nbuckets);
        int dblocks = (N + 127) / 128;
        dense1_mfma_kernel<<<dblocks, 256, 0, stream>>>(x, W_self1, W_neigh1, b1,
                                                        bufA, t1n, N);
        agg64_fused_kernel<<<(N * 64 + 255) / 256, 256, 0, stream>>>(
            t1n, bufA, row_start, csr_src, W_self2, W_neigh2, b2, out, t2n, N);
        agg32_kernel<<<(N * 64 + 255) / 256, 256, 0, stream>>>(out, t2n,
                                                               row_start, csr_src, N);
    } else {
        // fallback: atomic path (~51.6 MB)
        float* deg = (float*)d_ws;
        float* agg = deg + N;
        float* h1  = agg + (size_t)N * NF;
        hipMemsetAsync(deg, 0, (size_t)(N + (size_t)N * NF) * sizeof(float), stream);
        deg_kernel<<<(E + 255) / 256, 256, 0, stream>>>(dst, deg, E);
        int at = E * NF;
        agg_atomic_kernel<<<(at + 255) / 256, 256, 0, stream>>>(x, src, dst, agg, E);
        layer1_fb_kernel<<<(N * NF + 255) / 256, 256, 0, stream>>>(x, agg, deg, W_self1,
                                                                   W_neigh1, b1, h1, N);
        hipMemsetAsync(agg, 0, (size_t)N * NF * sizeof(float), stream);
        agg_atomic_kernel<<<(at + 255) / 256, 256, 0, stream>>>(h1, src, dst, agg, E);
        layer2_fb_kernel<<<(N * 32 + 255) / 256, 256, 0, stream>>>(h1, agg, deg, W_self2,
                                                                   W_neigh2, b2, out, N);
    }
}

// Round 10
// 238.711 us; speedup vs baseline: 1.2076x; 1.2076x over previous
//
#include <hip/hip_runtime.h>
#include <hip/hip_bf16.h>

// GraphSAGE 2-layer forward. N=100000, E=1250000, 64 -> 64 -> 32, fp32.
//
// Round-10: round-8 structure (proven 242.8 us) + 128B-aligned gather tables
// (t1n rows were 96 mod 128 -> every gather straddled 2 cachelines), s2 in
// d_out, P1_CHUNK 8192. Round-9 lesson: per-lane arrays >32 floats spill
// (VGPR=52 proved wcol[64] never lived in registers) - no mega-fusion.
//   zero    : gcursor = 0
//   p1      : bucket edges by dst>>8, pack (src<<8)|rel
//   p2      : per-bucket base (inline prefix) + LDS count/scan -> row_start + csr
//   dense1  : bufA = x@Ws1+b1 (f32), t1n = bf16(x@Wn1)  (MFMA split-bf16)
//   agg64   : bufA = relu(bufA + mean t1n[src])  (ILP-2, in place)
//   dense2  : d_out = h1@Ws2+b2 (f32), t2n = bf16(h1@Wn2)
//   agg32   : d_out += mean t2n[src]             (ILP-2, in place)

#define NF 64
#define BW 256            // bucket width (nodes); rel = dst & 255
#define BSH 8
#define MAXB 512          // max buckets (LDS arrays)
#define CAPMAX 8192       // max edges per bucket region (mean 3197)
#define P1_CHUNK 8192

typedef __attribute__((ext_vector_type(8))) short short8;
typedef __attribute__((ext_vector_type(8))) unsigned short ushort8v;
typedef __attribute__((ext_vector_type(4))) float floatx4;

__device__ __forceinline__ short bf16hi(float v) {
    __hip_bfloat16 h = __float2bfloat16(v);
    return *(short*)&h;
}
__device__ __forceinline__ float bf2f(short s) {
    __hip_bfloat16 h = *(__hip_bfloat16*)&s;
    return __bfloat162float(h);
}
__device__ __forceinline__ float bits2f(unsigned short u) {
    unsigned int x = ((unsigned int)u) << 16;
    union { unsigned int i; float f; } c; c.i = x; return c.f;
}

// ---------------- zero ----------------

__global__ __launch_bounds__(512) void zero_kernel(int* __restrict__ g) {
    if (threadIdx.x < MAXB) g[threadIdx.x] = 0;
}

// ---------------- CSR build: counting sort ----------------

__global__ __launch_bounds__(256) void p1_bucket_kernel(const int* __restrict__ src,
                                                        const int* __restrict__ dst,
                                                        int* __restrict__ gcursor,
                                                        unsigned* __restrict__ bucket,
                                                        int E, int nbuckets) {
    __shared__ int cnt[MAXB];
    __shared__ int cbase[MAXB];
    const int beg = blockIdx.x * P1_CHUNK;
    const int end = min(E, beg + P1_CHUNK);
    for (int i = threadIdx.x; i < nbuckets; i += 256) cnt[i] = 0;
    __syncthreads();
    for (int e = beg + threadIdx.x; e < end; e += 256)
        atomicAdd(&cnt[dst[e] >> BSH], 1);
    __syncthreads();
    for (int i = threadIdx.x; i < nbuckets; i += 256) {
        int c = cnt[i];
        cbase[i] = c ? atomicAdd(&gcursor[i], c) : 0;
        cnt[i] = 0;                              // reuse as local cursor
    }
    __syncthreads();
    for (int e = beg + threadIdx.x; e < end; e += 256) {
        int d = dst[e];
        int r = d >> BSH;
        int p = cbase[r] + atomicAdd(&cnt[r], 1);
        if (p < CAPMAX)                          // clamp: no OOB even if skewed
            bucket[(size_t)r * CAPMAX + p] = ((unsigned)src[e] << BSH) | (unsigned)(d & (BW - 1));
    }
}

// p2: one block per 256-node bucket; exclusive row_start segment + csr window.
__global__ __launch_bounds__(256) void p2_csr_kernel(const unsigned* __restrict__ bucket,
                                                     const int* __restrict__ gcursor,
                                                     int* __restrict__ row_start,
                                                     int* __restrict__ csr_src,
                                                     int N, int nbuckets) {
    __shared__ unsigned stage[CAPMAX];   // 32 KB
    __shared__ int cnt[BW];
    __shared__ int excl[BW];
    const int r = blockIdx.x;
    const int tid = threadIdx.x;

    // base = sum_{i<r} min(gcursor[i], CAPMAX)   (excl[] as scratch)
    int partial = 0;
    for (int i = tid; i < r; i += 256) partial += min(gcursor[i], CAPMAX);
    excl[tid] = partial;
    __syncthreads();
    for (int off = 128; off > 0; off >>= 1) {
        if (tid < off) excl[tid] += excl[tid + off];
        __syncthreads();
    }
    const int base = excl[0];
    const int sz = min(gcursor[r], CAPMAX);
    const unsigned* bsrc = bucket + (size_t)r * CAPMAX;
    __syncthreads();

    cnt[tid] = 0;
    __syncthreads();
    for (int i = tid; i < sz; i += 256) {
        unsigned v = bsrc[i];
        stage[i] = v;
        atomicAdd(&cnt[v & (BW - 1)], 1);
    }
    __syncthreads();
    // inclusive scan (Hillis-Steele, 1 elem/thread since BW == blockDim)
    excl[tid] = cnt[tid];
    __syncthreads();
    for (int off = 1; off < BW; off <<= 1) {
        int v0 = (tid >= off) ? excl[tid - off] : 0;
        __syncthreads();
        excl[tid] += v0;
        __syncthreads();
    }
    int node = r * BW + tid;
    if (node < N) row_start[node] = base + excl[tid] - cnt[tid];
    if (r == nbuckets - 1 && tid == 0) row_start[N] = base + sz;
    __syncthreads();
    cnt[tid] = excl[tid] - cnt[tid];             // exclusive cursors
    __syncthreads();
    for (int i = tid; i < sz; i += 256) {
        unsigned v = stage[i];
        int p = atomicAdd(&cnt[v & (BW - 1)], 1);
        csr_src[base + p] = (int)(v >> BSH);     // window owned by this block only
    }
}

// ---------------- MFMA dense: [N][64] @ [64][NT*16] ----------
// A layout: A[m=lane&15][k=(lane>>4)*8+j]; C/D: col=lane&15, row=(lane>>4)*4+reg.
// Weights split+transposed to bf16 hi/lo in LDS ([n][72] pad, 2-way banks free).
// Tiles t<NSELF -> f32 out + bias; t>=NSELF -> bf16 out (neighbor transform).

template<int NT, int NSELF>
__global__ __launch_bounds__(256) void dense_mfma_kernel(
        const float* __restrict__ X,                 // [N][64]
        const float* __restrict__ Wself,             // [64][HALF] k-major
        const float* __restrict__ Wneigh,            // [64][HALF] k-major
        const float* __restrict__ bias,              // [NSELF*16]
        float* __restrict__ outA,                    // row stride sA
        unsigned short* __restrict__ outB,           // row stride sB (bf16 bits)
        int sA, int sB, int N) {
    constexpr int NO = NT * 16;                      // out cols total (128 / 64)
    constexpr int HALF = NO / 2;
    __shared__ unsigned short wh[NO * 72];
    __shared__ unsigned short wl[NO * 72];
    const int tid = threadIdx.x;
    for (int i = tid; i < NO * 64; i += 256) {
        int n = i & (NO - 1), k = i / NO;            // consecutive tid -> coalesced
        float v = (n < HALF) ? Wself[k * HALF + n] : Wneigh[k * HALF + (n - HALF)];
        short hv = bf16hi(v);
        wh[n * 72 + k] = (unsigned short)hv;
        wl[n * 72 + k] = (unsigned short)bf16hi(v - bf2f(hv));
    }

    const int lane = tid & 63;
    const int wid  = tid >> 6;
    const int m = lane & 15, quad = lane >> 4;
    const int rowblk = blockIdx.x * 128 + wid * 32;

    floatx4 acc[2][NT];
    #pragma unroll
    for (int rt = 0; rt < 2; ++rt)
        #pragma unroll
        for (int t = 0; t < NT; ++t) acc[rt][t] = (floatx4)(0.f);

    short8 ah[2][2], al[2][2];   // [rowset][k-half]
    #pragma unroll
    for (int rt = 0; rt < 2; ++rt) {
        int r = rowblk + rt * 16 + m;
        if (r >= N) r = N - 1;                       // clamped load, store guarded
        const float* xp = X + (size_t)r * 64 + quad * 8;
        #pragma unroll
        for (int h = 0; h < 2; ++h) {
            floatx4 f0 = *(const floatx4*)(xp + h * 32);
            floatx4 f1 = *(const floatx4*)(xp + h * 32 + 4);
            short8 hi, lo;
            #pragma unroll
            for (int j = 0; j < 4; ++j) {
                short hv = bf16hi(f0[j]);
                hi[j] = hv; lo[j] = bf16hi(f0[j] - bf2f(hv));
                short hv2 = bf16hi(f1[j]);
                hi[4 + j] = hv2; lo[4 + j] = bf16hi(f1[j] - bf2f(hv2));
            }
            ah[rt][h] = hi; al[rt][h] = lo;
        }
    }
    __syncthreads();                                 // weights staged

    #pragma unroll
    for (int t = 0; t < NT; ++t) {
        int n = t * 16 + m;
        const unsigned short* ph = wh + n * 72 + quad * 8;
        const unsigned short* pl = wl + n * 72 + quad * 8;
        #pragma unroll
        for (int h = 0; h < 2; ++h) {
            short8 bh = *(const short8*)(ph + h * 32);
            short8 bl = *(const short8*)(pl + h * 32);
            #pragma unroll
            for (int rt = 0; rt < 2; ++rt) {
                acc[rt][t] = __builtin_amdgcn_mfma_f32_16x16x32_bf16(ah[rt][h], bh, acc[rt][t], 0, 0, 0);
                acc[rt][t] = __builtin_amdgcn_mfma_f32_16x16x32_bf16(al[rt][h], bh, acc[rt][t], 0, 0, 0);
                acc[rt][t] = __builtin_amdgcn_mfma_f32_16x16x32_bf16(ah[rt][h], bl, acc[rt][t], 0, 0, 0);
            }
        }
    }

    #pragma unroll
    for (int rt = 0; rt < 2; ++rt) {
        #pragma unroll
        for (int t = 0; t < NT; ++t) {
            #pragma unroll
            for (int r4 = 0; r4 < 4; ++r4) {
                int row = rowblk + rt * 16 + quad * 4 + r4;
                if (row < N) {
                    if (t < NSELF) {
                        int col = t * 16 + m;
                        outA[(size_t)row * sA + col] = acc[rt][t][r4] + bias[col];
                    } else {
                        int col = (t - NSELF) * 16 + m;
                        outB[(size_t)row * sB + col] = (unsigned short)bf16hi(acc[rt][t][r4]);
                    }
                }
            }
        }
    }
}

// ---------------- CSR aggregation (bf16 gathers, wide waves, ILP-2) ----------

// bufA[n] = relu(bufA[n] + mean_s t1n[s]); 8 groups of 8 lanes, 16 rows in flight
__global__ __launch_bounds__(256) void agg64_kernel(const unsigned short* __restrict__ t1n,
                                                    float* __restrict__ xs_io,
                                                    const int* __restrict__ row_start,
                                                    const int* __restrict__ csr_src, int N) {
    int n = (blockIdx.x * blockDim.x + threadIdx.x) >> 6;
    if (n >= N) return;
    int lane = threadIdx.x & 63;
    int g = lane >> 3, c = lane & 7;                 // lane covers feats c*8..c*8+7
    int beg = row_start[n], end = row_start[n + 1];
    float acc[8] = {0.f, 0.f, 0.f, 0.f, 0.f, 0.f, 0.f, 0.f};
    for (int j = beg + g; j < end; j += 16) {
        int j2 = j + 8;
        int s0 = csr_src[j];
        ushort8v u0 = *(const ushort8v*)(t1n + (size_t)s0 * 64 + c * 8);
        if (j2 < end) {
            int s1 = csr_src[j2];
            ushort8v u1 = *(const ushort8v*)(t1n + (size_t)s1 * 64 + c * 8);
            #pragma unroll
            for (int i = 0; i < 8; ++i) acc[i] += bits2f(u0[i]) + bits2f(u1[i]);
        } else {
            #pragma unroll
            for (int i = 0; i < 8; ++i) acc[i] += bits2f(u0[i]);
        }
    }
    #pragma unroll
    for (int i = 0; i < 8; ++i) {
        float v = acc[i];
        v += __shfl_xor(v, 8);
        v += __shfl_xor(v, 16);
        v += __shfl_xor(v, 32);
        acc[i] = v;
    }
    if (g == 0) {
        float inv = 1.0f / fmaxf((float)(end - beg), 1.0f);
        size_t o = (size_t)n * 64 + c * 8;
        floatx4 x0 = *(const floatx4*)(xs_io + o);
        floatx4 x1 = *(const floatx4*)(xs_io + o + 4);
        floatx4 r0, r1;
        #pragma unroll
        for (int i = 0; i < 4; ++i) {
            r0[i] = fmaxf(x0[i] + acc[i] * inv, 0.f);
            r1[i] = fmaxf(x1[i] + acc[4 + i] * inv, 0.f);
        }
        *(floatx4*)(xs_io + o) = r0;
        *(floatx4*)(xs_io + o + 4) = r1;
    }
}

// io[n] += mean_s t2n[s]; 16 groups of 4 lanes, 32 rows in flight; in place
__global__ __launch_bounds__(256) void agg32_kernel(float* io,  // [N][32] (d_out)
                                                    const unsigned short* __restrict__ t2n,
                                                    const int* __restrict__ row_start,
                                                    const int* __restrict__ csr_src, int N) {
    int n = (blockIdx.x * blockDim.x + threadIdx.x) >> 6;
    if (n >= N) return;
    int lane = threadIdx.x & 63;
    int g = lane >> 2, c = lane & 3;                 // lane covers feats c*8..c*8+7
    int beg = row_start[n], end = row_start[n + 1];
    float acc[8] = {0.f, 0.f, 0.f, 0.f, 0.f, 0.f, 0.f, 0.f};
    for (int j = beg + g; j < end; j += 32) {
        int j2 = j + 16;
        int s0 = csr_src[j];
        ushort8v u0 = *(const ushort8v*)(t2n + (size_t)s0 * 32 + c * 8);
        if (j2 < end) {
            int s1 = csr_src[j2];
            ushort8v u1 = *(const ushort8v*)(t2n + (size_t)s1 * 32 + c * 8);
            #pragma unroll
            for (int i = 0; i < 8; ++i) acc[i] += bits2f(u0[i]) + bits2f(u1[i]);
        } else {
            #pragma unroll
            for (int i = 0; i < 8; ++i) acc[i] += bits2f(u0[i]);
        }
    }
    #pragma unroll
    for (int i = 0; i < 8; ++i) {
        float v = acc[i];
        v += __shfl_xor(v, 4);
        v += __shfl_xor(v, 8);
        v += __shfl_xor(v, 16);
        v += __shfl_xor(v, 32);
        acc[i] = v;
    }
    if (g == 0) {
        float inv = 1.0f / fmaxf((float)(end - beg), 1.0f);
        size_t o = (size_t)n * 32 + c * 8;
        floatx4 s0 = *(const floatx4*)(io + o);
        floatx4 s1 = *(const floatx4*)(io + o + 4);
        floatx4 r0, r1;
        #pragma unroll
        for (int i = 0; i < 4; ++i) {
            r0[i] = s0[i] + acc[i] * inv;
            r1[i] = s1[i] + acc[4 + i] * inv;
        }
        *(floatx4*)(io + o) = r0;
        *(floatx4*)(io + o + 4) = r1;
    }
}

// ---------------- fallback (round-2 atomic path) ----------------

__global__ __launch_bounds__(256) void deg_kernel(const int* __restrict__ dst,
                                                  float* __restrict__ deg, int E) {
    int e = blockIdx.x * blockDim.x + threadIdx.x;
    if (e < E) atomicAdd(&deg[dst[e]], 1.0f);
}

__global__ __launch_bounds__(256) void agg_atomic_kernel(const float* __restrict__ feats,
                                                         const int* __restrict__ src,
                                                         const int* __restrict__ dst,
                                                         float* __restrict__ agg, int E) {
    int tid = blockIdx.x * blockDim.x + threadIdx.x;
    if (tid >= E * NF) return;
    int e = tid >> 6, f = tid & 63;
    atomicAdd(&agg[(size_t)dst[e] * NF + f], feats[(size_t)src[e] * NF + f]);
}

__global__ __launch_bounds__(256) void layer1_fb_kernel(const float* __restrict__ x,
                                                        const float* __restrict__ agg,
                                                        const float* __restrict__ deg,
                                                        const float* __restrict__ Wself,
                                                        const float* __restrict__ Wneigh,
                                                        const float* __restrict__ b,
                                                        float* __restrict__ h1, int N) {
    int tid = blockIdx.x * blockDim.x + threadIdx.x;
    if (tid >= N * NF) return;
    int n = tid >> 6, c = tid & 63;
    float inv = 1.0f / fmaxf(deg[n], 1.0f);
    const float* xrow = x + (size_t)n * NF;
    const float* arow = agg + (size_t)n * NF;
    float acc = b[c];
    #pragma unroll
    for (int k = 0; k < NF; ++k) {
        acc += xrow[k] * Wself[k * NF + c];
        acc += (arow[k] * inv) * Wneigh[k * NF + c];
    }
    h1[tid] = fmaxf(acc, 0.f);
}

__global__ __launch_bounds__(256) void layer2_fb_kernel(const float* __restrict__ h1,
                                                        const float* __restrict__ agg,
                                                        const float* __restrict__ deg,
                                                        const float* __restrict__ Wself,
                                                        const float* __restrict__ Wneigh,
                                                        const float* __restrict__ b,
                                                        float* __restrict__ out, int N) {
    int tid = blockIdx.x * blockDim.x + threadIdx.x;
    if (tid >= N * 32) return;
    int n = tid >> 5, c = tid & 31;
    float inv = 1.0f / fmaxf(deg[n], 1.0f);
    const float* hrow = h1 + (size_t)n * NF;
    const float* arow = agg + (size_t)n * NF;
    float acc = b[c];
    #pragma unroll
    for (int k = 0; k < NF; ++k) {
        acc += hrow[k] * Wself[k * 32 + c];
        acc += (arow[k] * inv) * Wneigh[k * 32 + c];
    }
    out[tid] = acc;
}

// ---------------- launch ----------------

extern "C" void kernel_launch(void* const* d_in, const int* in_sizes, int n_in,
                              void* d_out, int out_size, void* d_ws, size_t ws_size,
                              hipStream_t stream) {
    const float* x        = (const float*)d_in[0];
    const int*   src      = (const int*)d_in[1];
    const int*   dst      = (const int*)d_in[2];
    const float* W_self1  = (const float*)d_in[3];
    const float* W_neigh1 = (const float*)d_in[4];
    const float* b1       = (const float*)d_in[5];
    const float* W_self2  = (const float*)d_in[6];
    const float* W_neigh2 = (const float*)d_in[7];
    const float* b2       = (const float*)d_in[8];
    float* out = (float*)d_out;

    const int N = in_sizes[0] / NF;          // 100000
    const int E = in_sizes[1];               // 1250000
    const int nbuckets = (N + BW - 1) / BW;  // 391

    // ws layout; gather tables 128B-aligned (round-9 audit: bufA was 96 mod 128
    // -> every t1n row straddled 2 cachelines)
    const size_t rsPad = ((size_t)N + 8) & ~7ull;
    int* gcursor   = (int*)d_ws;                      // [MAXB]
    int* row_start = gcursor + MAXB;                  // [N+1] padded
    int* csr_src   = row_start + rsPad;               // [E]
    uintptr_t pa = (uintptr_t)(csr_src + (((size_t)E + 7) & ~7ull));
    pa = (pa + 127) & ~(uintptr_t)127;                // 128B align
    float* bufA = (float*)pa;                         // [N][64] f32, xs -> h1
    unsigned* bucket = (unsigned*)bufA;               // [nbuckets][CAPMAX], dead before dense1
    unsigned short* t1n = (unsigned short*)(bufA + (size_t)N * NF);  // [N][64] bf16, 128B rows
    unsigned short* t2n = t1n + (size_t)N * NF;                      // [N][32] bf16, 64B rows
    size_t need = (size_t)((char*)(t2n + (size_t)N * 32) - (char*)d_ws);  // ~50.2 MB

    bool fast = ws_size >= need
             && nbuckets <= MAXB
             && (size_t)nbuckets * CAPMAX <= (size_t)N * NF      // bucket fits in bufA alias
             && (size_t)E * 2 / (size_t)nbuckets <= CAPMAX       // 2x headroom over mean
             && N < (1 << 24)                                    // src fits in 24 bits
             && out_size >= N * 32;

    if (fast) {
        zero_kernel<<<1, 512, 0, stream>>>(gcursor);
        p1_bucket_kernel<<<(E + P1_CHUNK - 1) / P1_CHUNK, 256, 0, stream>>>(
            src, dst, gcursor, bucket, E, nbuckets);
        p2_csr_kernel<<<nbuckets, 256, 0, stream>>>(bucket, gcursor,
                                                    row_start, csr_src, N, nbuckets);
        int dblocks = (N + 127) / 128;
        // layer 1
        dense_mfma_kernel<8, 4><<<dblocks, 256, 0, stream>>>(x, W_self1, W_neigh1, b1,
                                                             bufA, t1n, 64, 64, N);
        agg64_kernel<<<(N * 64 + 255) / 256, 256, 0, stream>>>(t1n, bufA,
                                                               row_start, csr_src, N);
        // layer 2 (self-part straight into d_out; agg32 updates in place)
        dense_mfma_kernel<4, 2><<<dblocks, 256, 0, stream>>>(bufA, W_self2, W_neigh2, b2,
                                                             out, t2n, 32, 32, N);
        agg32_kernel<<<(N * 64 + 255) / 256, 256, 0, stream>>>(out, t2n,
                                                               row_start, csr_src, N);
    } else {
        // fallback: atomic path (~51.6 MB)
        float* deg = (float*)d_ws;
        float* agg = deg + N;
        float* h1  = agg + (size_t)N * NF;
        hipMemsetAsync(deg, 0, (size_t)(N + (size_t)N * NF) * sizeof(float), stream);
        deg_kernel<<<(E + 255) / 256, 256, 0, stream>>>(dst, deg, E);
        int at = E * NF;
        agg_atomic_kernel<<<(at + 255) / 256, 256, 0, stream>>>(x, src, dst, agg, E);
        layer1_fb_kernel<<<(N * NF + 255) / 256, 256, 0, stream>>>(x, agg, deg, W_self1,
                                                                   W_neigh1, b1, h1, N);
        hipMemsetAsync(agg, 0, (size_t)N * NF * sizeof(float), stream);
        agg_atomic_kernel<<<(at + 255) / 256, 256, 0, stream>>>(h1, src, dst, agg, E);
        layer2_fb_kernel<<<(N * 32 + 255) / 256, 256, 0, stream>>>(h1, agg, deg, W_self2,
                                                                   W_neigh2, b2, out, N);
    }
}